// Round 2
// baseline (681.509 us; speedup 1.0000x reference)
//
#include <hip/hip_runtime.h>

// NodeGNN: h = lrelu(lrelu(x@W1+b1)@W2+b2); 2x GCNConv(16->16) over E=6.4M edges
// + self loops with symmetric norm; out = sum(h@pw+pb, -1). Returns (out[N], h[N,16]).
//
// R6b: L2-resident gather (compile fix: nontemporal store needs a clang ext-vector,
// not HIP float2). The random-gather table was 6.4MB (N x 32B bf16) — does NOT fit
// a 4MB per-XCD L2 (measured ~69% hit rate, 280MB L2-miss traffic/gather, 3.1 TB/s
// fill plateau). Split features into two half-tables of N x 16B (3.2MB, L2-resident)
// and gather in two passes. dinv is folded into the stored rows (row = hw*dinv in
// bf16) killing the per-edge random dinv stream; csr reads and agg writes are
// nontemporal so streaming doesn't evict the table. Partition/CSR chain hoisted
// before the MLP so dinv exists at hw-time (X aliasing: pairs -> h -> agg).

#define NEG 0.01f
#define SHIFT 9                 // 512 nodes per bucket
#define BNODES (1 << SHIFT)
#define BMAX 512                // max buckets (N <= 262144)
#define PCHUNK 8192             // edges per partition block

typedef __attribute__((ext_vector_type(8))) short short8;
typedef __attribute__((ext_vector_type(4))) float floatx4;
typedef __attribute__((ext_vector_type(2))) float floatx2;
typedef __attribute__((ext_vector_type(4))) unsigned short us4;
typedef __attribute__((ext_vector_type(8))) unsigned short us8;

__device__ __forceinline__ float lrelu(float v) { return v >= 0.0f ? v : NEG * v; }

__device__ __forceinline__ unsigned short f2bf(float f) {
    unsigned int u = __float_as_uint(f);
    u += 0x7fffu + ((u >> 16) & 1u);          // round-to-nearest-even
    return (unsigned short)(u >> 16);
}
__device__ __forceinline__ float bflo(unsigned int u) { return __uint_as_float(u << 16); }
__device__ __forceinline__ float bfhi(unsigned int u) { return __uint_as_float(u & 0xffff0000u); }

// ---------------------------------------------------------------------------
// K-prep: bf16-transposed weights. W1T[n][k] = bf16(W1[k][n]) (256x128),
// W2T[c][k] = bf16(W2[k][c]) (16x256).
// ---------------------------------------------------------------------------
__global__ void prep_kernel(const float* __restrict__ W1, const float* __restrict__ W2,
                            unsigned short* __restrict__ W1T, unsigned short* __restrict__ W2T)
{
    const int idx = blockIdx.x * 256 + threadIdx.x;
    const int stride = gridDim.x * 256;
    for (int i = idx; i < 256 * 128; i += stride) {
        int n = i >> 7, k = i & 127;
        W1T[i] = f2bf(W1[k * 256 + n]);
    }
    for (int i = idx; i < 16 * 256; i += stride) {
        int c = i >> 8, k = i & 255;
        W2T[i] = f2bf(W2[k * 16 + c]);
    }
}

// ---------------------------------------------------------------------------
// K1: MFMA MLP. Block = 256 threads (4 waves), 64 nodes/block. (unchanged R3)
// ---------------------------------------------------------------------------
__global__ __launch_bounds__(256, 3) void mlp_mfma(
    const float* __restrict__ x, const unsigned short* __restrict__ W1T,
    const float* __restrict__ b1, const unsigned short* __restrict__ W2T,
    const float* __restrict__ b2, float* __restrict__ h, int N)
{
    __shared__ unsigned short xbf[64][136];   // 17.0 KB
    __shared__ unsigned short h1s[64][264];   // 33.8 KB

    const int tid  = threadIdx.x;
    const int n0   = blockIdx.x * 64;
    const int lane = tid & 63;
    const int lr   = lane & 15;
    const int quad = lane >> 4;
    const int wv   = tid >> 6;

    {
        const float4* xg = (const float4*)(x + (size_t)n0 * 128);
#pragma unroll
        for (int i = 0; i < 8; ++i) {
            int f = tid + 256 * i;
            float4 v = xg[f];
            int r = f >> 5, c = (f & 31) * 4;
            us4 p;
            p.x = f2bf(v.x); p.y = f2bf(v.y); p.z = f2bf(v.z); p.w = f2bf(v.w);
            *(us4*)&xbf[r][c] = p;
        }
    }
    __syncthreads();

    short8 af[4][4];
#pragma unroll
    for (int m = 0; m < 4; ++m)
#pragma unroll
        for (int kt = 0; kt < 4; ++kt)
            af[m][kt] = *(const short8*)&xbf[m * 16 + lr][kt * 32 + quad * 8];

    floatx4 acc[4][4];
#pragma unroll
    for (int n = 0; n < 4; ++n)
#pragma unroll
        for (int m = 0; m < 4; ++m)
            acc[n][m] = (floatx4){0.f, 0.f, 0.f, 0.f};

    const int nbase = wv * 64;
#pragma unroll
    for (int n = 0; n < 4; ++n) {
        const unsigned short* bp = &W1T[(size_t)(nbase + n * 16 + lr) * 128 + quad * 8];
        short8 bfr[4];
#pragma unroll
        for (int kt = 0; kt < 4; ++kt) bfr[kt] = *(const short8*)(bp + kt * 32);
#pragma unroll
        for (int kt = 0; kt < 4; ++kt)
#pragma unroll
            for (int m = 0; m < 4; ++m)
                acc[n][m] = __builtin_amdgcn_mfma_f32_16x16x32_bf16(
                    af[m][kt], bfr[kt], acc[n][m], 0, 0, 0);
    }

#pragma unroll
    for (int n = 0; n < 4; ++n) {
        float bc = b1[nbase + n * 16 + lr];
#pragma unroll
        for (int m = 0; m < 4; ++m)
#pragma unroll
            for (int reg = 0; reg < 4; ++reg) {
                float v = lrelu(acc[n][m][reg] + bc);
                h1s[m * 16 + quad * 4 + reg][nbase + n * 16 + lr] = f2bf(v);
            }
    }
    __syncthreads();

    floatx4 acc2 = (floatx4){0.f, 0.f, 0.f, 0.f};
#pragma unroll
    for (int kt = 0; kt < 8; ++kt) {
        short8 a2 = *(const short8*)&h1s[wv * 16 + lr][kt * 32 + quad * 8];
        short8 b2f = *(const short8*)&W2T[lr * 256 + kt * 32 + quad * 8];
        acc2 = __builtin_amdgcn_mfma_f32_16x16x32_bf16(a2, b2f, acc2, 0, 0, 0);
    }
    float bb = b2[lr];
#pragma unroll
    for (int reg = 0; reg < 4; ++reg) {
        int r = n0 + wv * 16 + quad * 4 + reg;
        h[(size_t)r * 16 + lr] = lrelu(acc2[reg] + bb);
    }
}

// ---------------------------------------------------------------------------
// K0: zero the global bucket counters
// ---------------------------------------------------------------------------
__global__ void zero_kernel(int* __restrict__ bcnt)
{
    bcnt[threadIdx.x] = 0;
}

// ---------------------------------------------------------------------------
// K2: per-bucket edge histogram (LDS-aggregated)
// ---------------------------------------------------------------------------
__global__ __launch_bounds__(256) void bucket_count(
    const int* __restrict__ eidx, int* __restrict__ bcnt, int E, int N, int B)
{
    __shared__ int hist[BMAX];
    const int t = threadIdx.x;
    for (int b = t; b < B; b += 256) hist[b] = 0;
    __syncthreads();

    const int stride = gridDim.x * 256;
    for (int e = blockIdx.x * 256 + t; e < E; e += stride) {
        int d = eidx[E + e];
        d = min(max(d, 0), N - 1);
        atomicAdd(&hist[d >> SHIFT], 1);
    }
    __syncthreads();
    for (int b = t; b < B; b += 256) {
        int c = hist[b];
        if (c) atomicAdd(&bcnt[b], c);
    }
}

// ---------------------------------------------------------------------------
// K3: single-block exclusive scan over bucket counts
// ---------------------------------------------------------------------------
__global__ __launch_bounds__(512) void scan_kernel(
    const int* __restrict__ bcnt, int* __restrict__ bbase, int* __restrict__ gcur, int B)
{
    __shared__ int s[BMAX];
    const int t = threadIdx.x;        // 512 threads
    int c = (t < B) ? bcnt[t] : 0;
    s[t] = c;
    __syncthreads();
#pragma unroll
    for (int off = 1; off < BMAX; off <<= 1) {
        int v = s[t];
        int u = (t >= off) ? s[t - off] : 0;
        __syncthreads();
        s[t] = v + u;
        __syncthreads();
    }
    if (t < B) {
        int excl = s[t] - c;
        bbase[t] = excl;
        gcur[t]  = excl;
    }
    if (t == 0) bbase[B] = s[BMAX - 1];
}

// ---------------------------------------------------------------------------
// K4: partition via block-level LDS counting sort + coalesced run flush.
// ---------------------------------------------------------------------------
__global__ __launch_bounds__(512) void partition_kernel(
    const int* __restrict__ eidx, int* __restrict__ gcur, int* __restrict__ pairs,
    int E, int N, int B)
{
    __shared__ int hist[BMAX];        // count -> cursor
    __shared__ int offx[BMAX + 1];    // exclusive local offsets (kept intact)
    __shared__ int basec[BMAX];       // global run base for this block
    __shared__ int sorted[PCHUNK];    // 32KB; doubles as scan scratch
    const int t  = threadIdx.x;
    const int e0 = blockIdx.x * PCHUNK;
    const int elim = min(PCHUNK, E - e0);

    hist[t] = 0;
    __syncthreads();
    for (int i = t; i < elim; i += 512) {
        int d = eidx[E + e0 + i];
        d = min(max(d, 0), N - 1);
        atomicAdd(&hist[d >> SHIFT], 1);
    }
    __syncthreads();

    int c = hist[t];
    sorted[t] = c;
    __syncthreads();
#pragma unroll
    for (int o = 1; o < BMAX; o <<= 1) {
        int v = sorted[t];
        int u = (t >= o) ? sorted[t - o] : 0;
        __syncthreads();
        sorted[t] = v + u;
        __syncthreads();
    }
    const int excl = sorted[t] - c;
    offx[t] = excl;
    if (t == 0) offx[BMAX] = elim;
    basec[t] = (t < B && c) ? atomicAdd(&gcur[t], c) : 0;
    hist[t] = excl;                   // becomes local cursor
    __syncthreads();

    for (int i = t; i < elim; i += 512) {
        int s = eidx[e0 + i];
        int d = eidx[E + e0 + i];
        s = min(max(s, 0), N - 1);
        d = min(max(d, 0), N - 1);
        int b = d >> SHIFT;
        int p = atomicAdd(&hist[b], 1);
        sorted[p] = (s << SHIFT) | (d & (BNODES - 1));
    }
    __syncthreads();

    for (int slot = t; slot < elim; slot += 512) {
        int v = sorted[slot];
        int l = 0, r = BMAX - 1;
#pragma unroll
        for (int it = 0; it < 9; ++it) {
            int m = (l + r + 1) >> 1;
            if (offx[m] <= slot) l = m; else r = m - 1;
        }
        pairs[basec[l] + (slot - offx[l])] = v;
    }
}

// ---------------------------------------------------------------------------
// K5: per-bucket counting sort -> csr, plus row_start/cnt/dinv
// ---------------------------------------------------------------------------
__global__ __launch_bounds__(512) void build_csr(
    const int* __restrict__ pairs, const int* __restrict__ bbase,
    int* __restrict__ row_start, int* __restrict__ cnt_out, float* __restrict__ dinv,
    int* __restrict__ csr, int N)
{
    __shared__ int cnt[BNODES];
    __shared__ int off[BNODES];
    const int b = blockIdx.x, t = threadIdx.x;   // 512 threads
    const int node0 = b << SHIFT;
    const int lo = bbase[b], hi = bbase[b + 1];

    cnt[t] = 0;
    __syncthreads();
    for (int e = lo + t; e < hi; e += 512)
        atomicAdd(&cnt[pairs[e] & (BNODES - 1)], 1);
    __syncthreads();

    int c = cnt[t];
    off[t] = c;
    __syncthreads();
#pragma unroll
    for (int o = 1; o < BNODES; o <<= 1) {
        int v = off[t];
        int u = (t >= o) ? off[t - o] : 0;
        __syncthreads();
        off[t] = v + u;
        __syncthreads();
    }
    const int excl = off[t] - c;
    const int node = node0 + t;
    if (node < N) {
        row_start[node] = lo + excl;
        cnt_out[node]   = c;
        dinv[node]      = rsqrtf((float)(c + 1));
    }
    cnt[t] = lo + excl;              // reuse as cursor
    __syncthreads();
    for (int e = lo + t; e < hi; e += 512) {
        int v = pairs[e];
        int p = atomicAdd(&cnt[v & (BNODES - 1)], 1);
        csr[p] = v >> SHIFT;
    }
}

// ---------------------------------------------------------------------------
// K6: hw = (optionally lrelu(in + bias_prev)) @ W[16x16], scaled by dinv[i],
// written as TWO bf16 half-tables (features 0..7 -> outA, 8..15 -> outB),
// 16B rows each (3.2MB per table: per-XCD-L2-resident for the gather).
// ---------------------------------------------------------------------------
__global__ void hw_kernel(const float* __restrict__ in, const float* __restrict__ W,
                          const float* __restrict__ bias, const float* __restrict__ dinv,
                          unsigned short* __restrict__ outA, unsigned short* __restrict__ outB,
                          int N, int apply)
{
    int i = blockIdx.x * 256 + threadIdx.x;
    if (i >= N) return;
    const float4* ir = (const float4*)(in + (size_t)i * 16);
    float4 r0 = ir[0], r1 = ir[1], r2 = ir[2], r3 = ir[3];
    float v[16] = {r0.x, r0.y, r0.z, r0.w, r1.x, r1.y, r1.z, r1.w,
                   r2.x, r2.y, r2.z, r2.w, r3.x, r3.y, r3.z, r3.w};
    if (apply) {
#pragma unroll
        for (int c = 0; c < 16; ++c) v[c] = lrelu(v[c] + bias[c]);
    }
    float o[16];
#pragma unroll
    for (int c = 0; c < 16; ++c) o[c] = 0.0f;
#pragma unroll
    for (int k = 0; k < 16; ++k) {
        float vk = v[k];
#pragma unroll
        for (int c = 0; c < 16; ++c) o[c] += vk * W[k * 16 + c];
    }
    float ds = dinv[i];
    us8 ra, rb;
#pragma unroll
    for (int c = 0; c < 8; ++c) { ra[c] = f2bf(o[c] * ds); rb[c] = f2bf(o[c + 8] * ds); }
    *(us8*)(outA + (size_t)i * 8) = ra;
    *(us8*)(outB + (size_t)i * 8) = rb;
}

// ---------------------------------------------------------------------------
// K7: half-feature gather over L2-resident 16B bf16 rows (pre-scaled by dinv).
// 4 lanes/node, lane cp owns features fofs+2cp, fofs+2cp+1.
// agg[d][fofs..fofs+7] = dinv_d * (row_d + sum_src row_src)   (rows = hw*dinv)
// csr loads and agg stores are nontemporal so streams don't evict the table.
// ---------------------------------------------------------------------------
__global__ __launch_bounds__(256) void gather_half(
    const unsigned short* __restrict__ hws, const float* __restrict__ dinv,
    const int* __restrict__ csr, const int* __restrict__ row_start,
    const int* __restrict__ cnt, float* __restrict__ agg, int N, int fofs)
{
    int t    = blockIdx.x * 256 + threadIdx.x;
    int node = t >> 2;
    int cp   = t & 3;
    if (node >= N) return;

    const unsigned int* rows = (const unsigned int*)hws;   // row i = 4 uints

    int   s0 = row_start[node];
    int   n  = cnt[node];
    float di = dinv[node];
    unsigned int self = rows[(size_t)node * 4 + cp];
    float a0 = bflo(self), a1 = bfhi(self);

    int j = 0;
    for (; j + 4 <= n; j += 4) {
        int sa = __builtin_nontemporal_load(&csr[s0 + j + 0]);
        int sb = __builtin_nontemporal_load(&csr[s0 + j + 1]);
        int sc = __builtin_nontemporal_load(&csr[s0 + j + 2]);
        int sd = __builtin_nontemporal_load(&csr[s0 + j + 3]);
        unsigned int va = rows[(size_t)sa * 4 + cp];
        unsigned int vb = rows[(size_t)sb * 4 + cp];
        unsigned int vc = rows[(size_t)sc * 4 + cp];
        unsigned int vd = rows[(size_t)sd * 4 + cp];
        a0 += bflo(va) + bflo(vb) + bflo(vc) + bflo(vd);
        a1 += bfhi(va) + bfhi(vb) + bfhi(vc) + bfhi(vd);
    }
    for (; j < n; ++j) {
        int s = __builtin_nontemporal_load(&csr[s0 + j]);
        unsigned int v = rows[(size_t)s * 4 + cp];
        a0 += bflo(v); a1 += bfhi(v);
    }
    floatx2 r;
    r.x = a0 * di; r.y = a1 * di;
    __builtin_nontemporal_store(r, (floatx2*)&agg[(size_t)node * 16 + fofs + cp * 2]);
}

// ---------------------------------------------------------------------------
// K8: final head. h = lrelu(agg + cb1); out = h . (pw[:,0]+pw[:,1]) + pb0+pb1
// ---------------------------------------------------------------------------
__global__ void final_kernel(const float* __restrict__ agg, const float* __restrict__ cb1,
                             const float* __restrict__ pw, const float* __restrict__ pb,
                             float* __restrict__ out, float* __restrict__ hout, int N)
{
    int i = blockIdx.x * 256 + threadIdx.x;
    if (i >= N) return;
    const float4* ar = (const float4*)(agg + (size_t)i * 16);
    float4 r0 = ar[0], r1 = ar[1], r2 = ar[2], r3 = ar[3];
    float v[16] = {r0.x, r0.y, r0.z, r0.w, r1.x, r1.y, r1.z, r1.w,
                   r2.x, r2.y, r2.z, r2.w, r3.x, r3.y, r3.z, r3.w};
    float s = pb[0] + pb[1];
#pragma unroll
    for (int c = 0; c < 16; ++c) {
        v[c] = lrelu(v[c] + cb1[c]);
        s += v[c] * (pw[c * 2] + pw[c * 2 + 1]);
    }
    out[i] = s;
    float4* hr = (float4*)(hout + (size_t)i * 16);
    hr[0] = make_float4(v[0],  v[1],  v[2],  v[3]);
    hr[1] = make_float4(v[4],  v[5],  v[6],  v[7]);
    hr[2] = make_float4(v[8],  v[9],  v[10], v[11]);
    hr[3] = make_float4(v[12], v[13], v[14], v[15]);
}

// ---------------------------------------------------------------------------
extern "C" void kernel_launch(void* const* d_in, const int* in_sizes, int n_in,
                              void* d_out, int out_size, void* d_ws, size_t ws_size,
                              hipStream_t stream)
{
    const float* x   = (const float*)d_in[0];
    const float* W1  = (const float*)d_in[1];
    const float* b1  = (const float*)d_in[2];
    const float* W2  = (const float*)d_in[3];
    const float* b2  = (const float*)d_in[4];
    const float* cw0 = (const float*)d_in[5];
    const float* cb0 = (const float*)d_in[6];
    const float* cw1 = (const float*)d_in[7];
    const float* cb1 = (const float*)d_in[8];
    const float* pw  = (const float*)d_in[9];
    const float* pb  = (const float*)d_in[10];
    const int*   eidx = (const int*)d_in[11];

    const int N = in_sizes[0] / 128;
    const int E = in_sizes[11] / 2;
    const int B = (N + BNODES - 1) >> SHIFT;

    // workspace carve-out (~60 MB); X region serves pairs -> h -> agg
    char* w = (char*)d_ws;
    unsigned short* hwsA = (unsigned short*)w; w += (size_t)N * 8 * 2;  // bf16 half rows
    unsigned short* hwsB = (unsigned short*)w; w += (size_t)N * 8 * 2;
    float* dinv    = (float*)w; w += (size_t)N * 4;
    int*   cnt     = (int*)w;   w += (size_t)N * 4;
    int*   row_st  = (int*)w;   w += (size_t)N * 4;
    int*   csr     = (int*)w;   w += (size_t)E * 4;
    char*  X       = w;         w += (size_t)E * 4;
    int*   bcnt    = (int*)w;   w += BMAX * 4;
    int*   bbase   = (int*)w;   w += (BMAX + 4) * 4;   // +4 keeps 16B alignment below
    int*   gcur    = (int*)w;   w += BMAX * 4;
    unsigned short* W1T = (unsigned short*)w; w += 256 * 128 * 2;  // 16B-aligned
    unsigned short* W2T = (unsigned short*)w; w += 16 * 256 * 2;

    int*   pairs = (int*)X;     // live: partition -> build_csr
    float* h     = (float*)X;   // live: mlp -> hw1 (pairs dead)
    float* agg   = (float*)X;   // live: gather1 -> final (h dead)

    float* out  = (float*)d_out;
    float* hout = out + N;

    const int nb_n = (N + 255) / 256;
    const int nb_g = (N * 4 + 255) / 256;
    const int nb_p = (E + PCHUNK - 1) / PCHUNK;

    // CSR chain first so dinv exists before hw_kernel folds it into the rows.
    zero_kernel<<<1, BMAX, 0, stream>>>(bcnt);
    bucket_count<<<1024, 256, 0, stream>>>(eidx, bcnt, E, N, B);
    scan_kernel<<<1, BMAX, 0, stream>>>(bcnt, bbase, gcur, B);
    partition_kernel<<<nb_p, 512, 0, stream>>>(eidx, gcur, pairs, E, N, B);
    build_csr<<<B, 512, 0, stream>>>(pairs, bbase, row_st, cnt, dinv, csr, N);

    prep_kernel<<<32, 256, 0, stream>>>(W1, W2, W1T, W2T);
    mlp_mfma<<<N / 64, 256, 0, stream>>>(x, W1T, b1, W2T, b2, h, N);   // pairs dead

    hw_kernel<<<nb_n, 256, 0, stream>>>(h, cw0, nullptr, dinv, hwsA, hwsB, N, 0);
    gather_half<<<nb_g, 256, 0, stream>>>(hwsA, dinv, csr, row_st, cnt, agg, N, 0); // h dead
    gather_half<<<nb_g, 256, 0, stream>>>(hwsB, dinv, csr, row_st, cnt, agg, N, 8);

    hw_kernel<<<nb_n, 256, 0, stream>>>(agg, cw1, cb0, dinv, hwsA, hwsB, N, 1);
    gather_half<<<nb_g, 256, 0, stream>>>(hwsA, dinv, csr, row_st, cnt, agg, N, 0);
    gather_half<<<nb_g, 256, 0, stream>>>(hwsB, dinv, csr, row_st, cnt, agg, N, 8);

    final_kernel<<<nb_n, 256, 0, stream>>>(agg, cb1, pw, pb, out, hout, N);
}

// Round 3
// 589.426 us; speedup vs baseline: 1.1562x; 1.1562x over previous
//
#include <hip/hip_runtime.h>

// NodeGNN: h = lrelu(lrelu(x@W1+b1)@W2+b2); 2x GCNConv(16->16) over E=6.4M edges
// + self loops with symmetric norm; out = sum(h@pw+pb, -1). Returns (out[N], h[N,16]).
//
// R7: source-half-split gather. R6 post-mortem: the gather is limited by per-CU
// random L1-fill throughput (~4.7 cyc/fill measured in R5), NOT L3 fill BW.
// R6's feature split kept fills/layer constant while halving concurrency -> 681us.
// R7 keeps ONE 32B bf16 row table with dinv folded (1 random fill per edge per
// layer, the minimum) and partitions each adjacency list by source half so each
// gather pass touches only a 3.2MB region (per-XCD-L2-resident). All N nodes
// active in both passes (8 lanes/node); csr read once per layer; pass1 merges
// pass0 partials and applies the destination dinv scale.

#define NEG 0.01f
#define SHIFT 9                 // 512 nodes per bucket
#define BNODES (1 << SHIFT)
#define BMAX 512                // max buckets (N <= 262144)
#define PCHUNK 8192             // edges per partition block

typedef __attribute__((ext_vector_type(8))) short short8;
typedef __attribute__((ext_vector_type(4))) float floatx4;
typedef __attribute__((ext_vector_type(2))) float floatx2;
typedef __attribute__((ext_vector_type(4))) unsigned short us4;
typedef __attribute__((ext_vector_type(8))) unsigned short us8;

__device__ __forceinline__ float lrelu(float v) { return v >= 0.0f ? v : NEG * v; }

__device__ __forceinline__ unsigned short f2bf(float f) {
    unsigned int u = __float_as_uint(f);
    u += 0x7fffu + ((u >> 16) & 1u);          // round-to-nearest-even
    return (unsigned short)(u >> 16);
}
__device__ __forceinline__ float bflo(unsigned int u) { return __uint_as_float(u << 16); }
__device__ __forceinline__ float bfhi(unsigned int u) { return __uint_as_float(u & 0xffff0000u); }

// ---------------------------------------------------------------------------
// K-prep: bf16-transposed weights. W1T[n][k] = bf16(W1[k][n]) (256x128),
// W2T[c][k] = bf16(W2[k][c]) (16x256).
// ---------------------------------------------------------------------------
__global__ void prep_kernel(const float* __restrict__ W1, const float* __restrict__ W2,
                            unsigned short* __restrict__ W1T, unsigned short* __restrict__ W2T)
{
    const int idx = blockIdx.x * 256 + threadIdx.x;
    const int stride = gridDim.x * 256;
    for (int i = idx; i < 256 * 128; i += stride) {
        int n = i >> 7, k = i & 127;
        W1T[i] = f2bf(W1[k * 256 + n]);
    }
    for (int i = idx; i < 16 * 256; i += stride) {
        int c = i >> 8, k = i & 255;
        W2T[i] = f2bf(W2[k * 16 + c]);
    }
}

// ---------------------------------------------------------------------------
// K1: MFMA MLP. Block = 256 threads (4 waves), 64 nodes/block. (unchanged R3)
// ---------------------------------------------------------------------------
__global__ __launch_bounds__(256, 3) void mlp_mfma(
    const float* __restrict__ x, const unsigned short* __restrict__ W1T,
    const float* __restrict__ b1, const unsigned short* __restrict__ W2T,
    const float* __restrict__ b2, float* __restrict__ h, int N)
{
    __shared__ unsigned short xbf[64][136];   // 17.0 KB
    __shared__ unsigned short h1s[64][264];   // 33.8 KB

    const int tid  = threadIdx.x;
    const int n0   = blockIdx.x * 64;
    const int lane = tid & 63;
    const int lr   = lane & 15;
    const int quad = lane >> 4;
    const int wv   = tid >> 6;

    {
        const float4* xg = (const float4*)(x + (size_t)n0 * 128);
#pragma unroll
        for (int i = 0; i < 8; ++i) {
            int f = tid + 256 * i;
            float4 v = xg[f];
            int r = f >> 5, c = (f & 31) * 4;
            us4 p;
            p.x = f2bf(v.x); p.y = f2bf(v.y); p.z = f2bf(v.z); p.w = f2bf(v.w);
            *(us4*)&xbf[r][c] = p;
        }
    }
    __syncthreads();

    short8 af[4][4];
#pragma unroll
    for (int m = 0; m < 4; ++m)
#pragma unroll
        for (int kt = 0; kt < 4; ++kt)
            af[m][kt] = *(const short8*)&xbf[m * 16 + lr][kt * 32 + quad * 8];

    floatx4 acc[4][4];
#pragma unroll
    for (int n = 0; n < 4; ++n)
#pragma unroll
        for (int m = 0; m < 4; ++m)
            acc[n][m] = (floatx4){0.f, 0.f, 0.f, 0.f};

    const int nbase = wv * 64;
#pragma unroll
    for (int n = 0; n < 4; ++n) {
        const unsigned short* bp = &W1T[(size_t)(nbase + n * 16 + lr) * 128 + quad * 8];
        short8 bfr[4];
#pragma unroll
        for (int kt = 0; kt < 4; ++kt) bfr[kt] = *(const short8*)(bp + kt * 32);
#pragma unroll
        for (int kt = 0; kt < 4; ++kt)
#pragma unroll
            for (int m = 0; m < 4; ++m)
                acc[n][m] = __builtin_amdgcn_mfma_f32_16x16x32_bf16(
                    af[m][kt], bfr[kt], acc[n][m], 0, 0, 0);
    }

#pragma unroll
    for (int n = 0; n < 4; ++n) {
        float bc = b1[nbase + n * 16 + lr];
#pragma unroll
        for (int m = 0; m < 4; ++m)
#pragma unroll
            for (int reg = 0; reg < 4; ++reg) {
                float v = lrelu(acc[n][m][reg] + bc);
                h1s[m * 16 + quad * 4 + reg][nbase + n * 16 + lr] = f2bf(v);
            }
    }
    __syncthreads();

    floatx4 acc2 = (floatx4){0.f, 0.f, 0.f, 0.f};
#pragma unroll
    for (int kt = 0; kt < 8; ++kt) {
        short8 a2 = *(const short8*)&h1s[wv * 16 + lr][kt * 32 + quad * 8];
        short8 b2f = *(const short8*)&W2T[lr * 256 + kt * 32 + quad * 8];
        acc2 = __builtin_amdgcn_mfma_f32_16x16x32_bf16(a2, b2f, acc2, 0, 0, 0);
    }
    float bb = b2[lr];
#pragma unroll
    for (int reg = 0; reg < 4; ++reg) {
        int r = n0 + wv * 16 + quad * 4 + reg;
        h[(size_t)r * 16 + lr] = lrelu(acc2[reg] + bb);
    }
}

// ---------------------------------------------------------------------------
// K0: zero the global bucket counters
// ---------------------------------------------------------------------------
__global__ void zero_kernel(int* __restrict__ bcnt)
{
    bcnt[threadIdx.x] = 0;
}

// ---------------------------------------------------------------------------
// K2: per-bucket edge histogram (LDS-aggregated)
// ---------------------------------------------------------------------------
__global__ __launch_bounds__(256) void bucket_count(
    const int* __restrict__ eidx, int* __restrict__ bcnt, int E, int N, int B)
{
    __shared__ int hist[BMAX];
    const int t = threadIdx.x;
    for (int b = t; b < B; b += 256) hist[b] = 0;
    __syncthreads();

    const int stride = gridDim.x * 256;
    for (int e = blockIdx.x * 256 + t; e < E; e += stride) {
        int d = eidx[E + e];
        d = min(max(d, 0), N - 1);
        atomicAdd(&hist[d >> SHIFT], 1);
    }
    __syncthreads();
    for (int b = t; b < B; b += 256) {
        int c = hist[b];
        if (c) atomicAdd(&bcnt[b], c);
    }
}

// ---------------------------------------------------------------------------
// K3: single-block exclusive scan over bucket counts
// ---------------------------------------------------------------------------
__global__ __launch_bounds__(512) void scan_kernel(
    const int* __restrict__ bcnt, int* __restrict__ bbase, int* __restrict__ gcur, int B)
{
    __shared__ int s[BMAX];
    const int t = threadIdx.x;        // 512 threads
    int c = (t < B) ? bcnt[t] : 0;
    s[t] = c;
    __syncthreads();
#pragma unroll
    for (int off = 1; off < BMAX; off <<= 1) {
        int v = s[t];
        int u = (t >= off) ? s[t - off] : 0;
        __syncthreads();
        s[t] = v + u;
        __syncthreads();
    }
    if (t < B) {
        int excl = s[t] - c;
        bbase[t] = excl;
        gcur[t]  = excl;
    }
    if (t == 0) bbase[B] = s[BMAX - 1];
}

// ---------------------------------------------------------------------------
// K4: partition via block-level LDS counting sort + coalesced run flush.
// ---------------------------------------------------------------------------
__global__ __launch_bounds__(512) void partition_kernel(
    const int* __restrict__ eidx, int* __restrict__ gcur, int* __restrict__ pairs,
    int E, int N, int B)
{
    __shared__ int hist[BMAX];        // count -> cursor
    __shared__ int offx[BMAX + 1];    // exclusive local offsets (kept intact)
    __shared__ int basec[BMAX];       // global run base for this block
    __shared__ int sorted[PCHUNK];    // 32KB; doubles as scan scratch
    const int t  = threadIdx.x;
    const int e0 = blockIdx.x * PCHUNK;
    const int elim = min(PCHUNK, E - e0);

    hist[t] = 0;
    __syncthreads();
    for (int i = t; i < elim; i += 512) {
        int d = eidx[E + e0 + i];
        d = min(max(d, 0), N - 1);
        atomicAdd(&hist[d >> SHIFT], 1);
    }
    __syncthreads();

    int c = hist[t];
    sorted[t] = c;
    __syncthreads();
#pragma unroll
    for (int o = 1; o < BMAX; o <<= 1) {
        int v = sorted[t];
        int u = (t >= o) ? sorted[t - o] : 0;
        __syncthreads();
        sorted[t] = v + u;
        __syncthreads();
    }
    const int excl = sorted[t] - c;
    offx[t] = excl;
    if (t == 0) offx[BMAX] = elim;
    basec[t] = (t < B && c) ? atomicAdd(&gcur[t], c) : 0;
    hist[t] = excl;                   // becomes local cursor
    __syncthreads();

    for (int i = t; i < elim; i += 512) {
        int s = eidx[e0 + i];
        int d = eidx[E + e0 + i];
        s = min(max(s, 0), N - 1);
        d = min(max(d, 0), N - 1);
        int b = d >> SHIFT;
        int p = atomicAdd(&hist[b], 1);
        sorted[p] = (s << SHIFT) | (d & (BNODES - 1));
    }
    __syncthreads();

    for (int slot = t; slot < elim; slot += 512) {
        int v = sorted[slot];
        int l = 0, r = BMAX - 1;
#pragma unroll
        for (int it = 0; it < 9; ++it) {
            int m = (l + r + 1) >> 1;
            if (offx[m] <= slot) l = m; else r = m - 1;
        }
        pairs[basec[l] + (slot - offx[l])] = v;
    }
}

// ---------------------------------------------------------------------------
// K5: per-bucket counting sort -> csr with per-node (src<Nhalf | src>=Nhalf)
// partition, plus row_start/cnt/cnt_lo/dinv.
// ---------------------------------------------------------------------------
__global__ __launch_bounds__(512) void build_csr(
    const int* __restrict__ pairs, const int* __restrict__ bbase,
    int* __restrict__ row_start, int* __restrict__ cnt_out, int* __restrict__ cntlo_out,
    float* __restrict__ dinv, int* __restrict__ csr, int N, int Nhalf)
{
    __shared__ int cnt[BNODES];
    __shared__ int off[BNODES];
    __shared__ int clo[BNODES];
    const int b = blockIdx.x, t = threadIdx.x;   // 512 threads
    const int node0 = b << SHIFT;
    const int lo = bbase[b], hi = bbase[b + 1];

    cnt[t] = 0;
    clo[t] = 0;
    __syncthreads();
    for (int e = lo + t; e < hi; e += 512) {
        int v = pairs[e];
        atomicAdd(&cnt[v & (BNODES - 1)], 1);
        if ((v >> SHIFT) < Nhalf) atomicAdd(&clo[v & (BNODES - 1)], 1);
    }
    __syncthreads();

    int c = cnt[t];
    off[t] = c;
    __syncthreads();
#pragma unroll
    for (int o = 1; o < BNODES; o <<= 1) {
        int v = off[t];
        int u = (t >= o) ? off[t - o] : 0;
        __syncthreads();
        off[t] = v + u;
        __syncthreads();
    }
    const int excl = off[t] - c;
    const int cl   = clo[t];
    const int node = node0 + t;
    if (node < N) {
        row_start[node]  = lo + excl;
        cnt_out[node]    = c;
        cntlo_out[node]  = cl;
        dinv[node]       = rsqrtf((float)(c + 1));
    }
    cnt[t] = lo + excl;              // lo-region cursor
    clo[t] = lo + excl + cl;         // hi-region cursor
    __syncthreads();
    for (int e = lo + t; e < hi; e += 512) {
        int v = pairs[e];
        int s = v >> SHIFT;
        int idx = v & (BNODES - 1);
        int p = (s < Nhalf) ? atomicAdd(&cnt[idx], 1) : atomicAdd(&clo[idx], 1);
        csr[p] = s;
    }
}

// ---------------------------------------------------------------------------
// K6: hw = (optionally lrelu(in + bias_prev)) @ W[16x16], scaled by dinv[i],
// stored as bf16 rows (32B/row, 6.4MB table; each gather pass touches one
// 3.2MB half -> per-XCD-L2-resident).
// ---------------------------------------------------------------------------
__global__ void hw_kernel(const float* __restrict__ in, const float* __restrict__ W,
                          const float* __restrict__ bias, const float* __restrict__ dinv,
                          unsigned short* __restrict__ out, int N, int apply)
{
    int i = blockIdx.x * 256 + threadIdx.x;
    if (i >= N) return;
    const float4* ir = (const float4*)(in + (size_t)i * 16);
    float4 r0 = ir[0], r1 = ir[1], r2 = ir[2], r3 = ir[3];
    float v[16] = {r0.x, r0.y, r0.z, r0.w, r1.x, r1.y, r1.z, r1.w,
                   r2.x, r2.y, r2.z, r2.w, r3.x, r3.y, r3.z, r3.w};
    if (apply) {
#pragma unroll
        for (int c = 0; c < 16; ++c) v[c] = lrelu(v[c] + bias[c]);
    }
    float o[16];
#pragma unroll
    for (int c = 0; c < 16; ++c) o[c] = 0.0f;
#pragma unroll
    for (int k = 0; k < 16; ++k) {
        float vk = v[k];
#pragma unroll
        for (int c = 0; c < 16; ++c) o[c] += vk * W[k * 16 + c];
    }
    float ds = dinv[i];
    us8 lo8, hi8;
#pragma unroll
    for (int c = 0; c < 8; ++c) { lo8[c] = f2bf(o[c] * ds); hi8[c] = f2bf(o[c + 8] * ds); }
    us8* orow = (us8*)(out + (size_t)i * 16);
    orow[0] = lo8;
    orow[1] = hi8;
}

// ---------------------------------------------------------------------------
// K7: gather pass over one source-half. 8 lanes/node, lane cp owns features
// 2cp,2cp+1. Rows are pre-scaled by dinv_src; pass 0 sums sources < Nhalf and
// writes raw partials; pass 1 sums the rest, merges partials, scales by dinv_d.
// Self term added in the pass whose region holds the node's own row.
// ---------------------------------------------------------------------------
__global__ __launch_bounds__(256) void gather_kernel(
    const unsigned short* __restrict__ hws, const float* __restrict__ dinv,
    const int* __restrict__ csr, const int* __restrict__ row_start,
    const int* __restrict__ cnt, const int* __restrict__ cntlo,
    float* __restrict__ agg, int N, int Nhalf, int pass)
{
    int t    = blockIdx.x * 256 + threadIdx.x;
    int node = t >> 3;
    int cp   = t & 7;
    if (node >= N) return;

    const unsigned int* rows = (const unsigned int*)hws;   // row i = 8 uints

    int s0 = row_start[node];
    int cl = cntlo[node];
    int n  = cnt[node];

    int jbeg = pass ? cl : 0;
    int jend = pass ? n  : cl;

    float a0 = 0.0f, a1 = 0.0f;
    // self row lives in the region matching its index half
    if ((pass == 0) == (node < Nhalf)) {
        unsigned int self = rows[(size_t)node * 8 + cp];
        a0 = bflo(self); a1 = bfhi(self);
    }

    int j = jbeg;
    for (; j + 4 <= jend; j += 4) {
        int sa = __builtin_nontemporal_load(&csr[s0 + j + 0]);
        int sb = __builtin_nontemporal_load(&csr[s0 + j + 1]);
        int sc = __builtin_nontemporal_load(&csr[s0 + j + 2]);
        int sd = __builtin_nontemporal_load(&csr[s0 + j + 3]);
        unsigned int va = rows[(size_t)sa * 8 + cp];
        unsigned int vb = rows[(size_t)sb * 8 + cp];
        unsigned int vc = rows[(size_t)sc * 8 + cp];
        unsigned int vd = rows[(size_t)sd * 8 + cp];
        a0 += bflo(va) + bflo(vb) + bflo(vc) + bflo(vd);
        a1 += bfhi(va) + bfhi(vb) + bfhi(vc) + bfhi(vd);
    }
    for (; j < jend; ++j) {
        int s = __builtin_nontemporal_load(&csr[s0 + j]);
        unsigned int v = rows[(size_t)s * 8 + cp];
        a0 += bflo(v); a1 += bfhi(v);
    }

    floatx2* slot = (floatx2*)&agg[(size_t)node * 16 + cp * 2];
    if (pass == 0) {
        floatx2 r; r.x = a0; r.y = a1;
        __builtin_nontemporal_store(r, slot);
    } else {
        floatx2 p = __builtin_nontemporal_load(slot);
        float di = dinv[node];
        floatx2 r; r.x = (p.x + a0) * di; r.y = (p.y + a1) * di;
        __builtin_nontemporal_store(r, slot);
    }
}

// ---------------------------------------------------------------------------
// K8: final head. h = lrelu(agg + cb1); out = h . (pw[:,0]+pw[:,1]) + pb0+pb1
// ---------------------------------------------------------------------------
__global__ void final_kernel(const float* __restrict__ agg, const float* __restrict__ cb1,
                             const float* __restrict__ pw, const float* __restrict__ pb,
                             float* __restrict__ out, float* __restrict__ hout, int N)
{
    int i = blockIdx.x * 256 + threadIdx.x;
    if (i >= N) return;
    const float4* ar = (const float4*)(agg + (size_t)i * 16);
    float4 r0 = ar[0], r1 = ar[1], r2 = ar[2], r3 = ar[3];
    float v[16] = {r0.x, r0.y, r0.z, r0.w, r1.x, r1.y, r1.z, r1.w,
                   r2.x, r2.y, r2.z, r2.w, r3.x, r3.y, r3.z, r3.w};
    float s = pb[0] + pb[1];
#pragma unroll
    for (int c = 0; c < 16; ++c) {
        v[c] = lrelu(v[c] + cb1[c]);
        s += v[c] * (pw[c * 2] + pw[c * 2 + 1]);
    }
    out[i] = s;
    float4* hr = (float4*)(hout + (size_t)i * 16);
    hr[0] = make_float4(v[0],  v[1],  v[2],  v[3]);
    hr[1] = make_float4(v[4],  v[5],  v[6],  v[7]);
    hr[2] = make_float4(v[8],  v[9],  v[10], v[11]);
    hr[3] = make_float4(v[12], v[13], v[14], v[15]);
}

// ---------------------------------------------------------------------------
extern "C" void kernel_launch(void* const* d_in, const int* in_sizes, int n_in,
                              void* d_out, int out_size, void* d_ws, size_t ws_size,
                              hipStream_t stream)
{
    const float* x   = (const float*)d_in[0];
    const float* W1  = (const float*)d_in[1];
    const float* b1  = (const float*)d_in[2];
    const float* W2  = (const float*)d_in[3];
    const float* b2  = (const float*)d_in[4];
    const float* cw0 = (const float*)d_in[5];
    const float* cb0 = (const float*)d_in[6];
    const float* cw1 = (const float*)d_in[7];
    const float* cb1 = (const float*)d_in[8];
    const float* pw  = (const float*)d_in[9];
    const float* pb  = (const float*)d_in[10];
    const int*   eidx = (const int*)d_in[11];

    const int N = in_sizes[0] / 128;
    const int E = in_sizes[11] / 2;
    const int B = (N + BNODES - 1) >> SHIFT;
    const int Nhalf = (N + 1) >> 1;

    // workspace carve-out (~61 MB); X region serves pairs -> h -> agg
    char* w = (char*)d_ws;
    unsigned short* hws = (unsigned short*)w; w += (size_t)N * 16 * 2;  // bf16 rows (32B)
    float* dinv    = (float*)w; w += (size_t)N * 4;
    int*   cnt     = (int*)w;   w += (size_t)N * 4;
    int*   row_st  = (int*)w;   w += (size_t)N * 4;
    int*   csr     = (int*)w;   w += (size_t)E * 4;
    char*  X       = w;         w += (size_t)E * 4;
    int*   bcnt    = (int*)w;   w += BMAX * 4;
    int*   bbase   = (int*)w;   w += (BMAX + 4) * 4;   // +4 keeps 16B alignment below
    int*   gcur    = (int*)w;   w += BMAX * 4;
    unsigned short* W1T = (unsigned short*)w; w += 256 * 128 * 2;  // 16B-aligned
    unsigned short* W2T = (unsigned short*)w; w += 16 * 256 * 2;
    int*   cntlo   = (int*)w;   w += (size_t)N * 4;

    int*   pairs = (int*)X;     // live: partition -> build_csr
    float* h     = (float*)X;   // live: mlp -> hw1 (pairs dead)
    float* agg   = (float*)X;   // live: gather -> final (h dead)

    float* out  = (float*)d_out;
    float* hout = out + N;

    const int nb_n = (N + 255) / 256;
    const int nb_g = (N * 8 + 255) / 256;
    const int nb_p = (E + PCHUNK - 1) / PCHUNK;

    // CSR chain first so dinv exists before hw_kernel folds it into the rows.
    zero_kernel<<<1, BMAX, 0, stream>>>(bcnt);
    bucket_count<<<1024, 256, 0, stream>>>(eidx, bcnt, E, N, B);
    scan_kernel<<<1, BMAX, 0, stream>>>(bcnt, bbase, gcur, B);
    partition_kernel<<<nb_p, 512, 0, stream>>>(eidx, gcur, pairs, E, N, B);
    build_csr<<<B, 512, 0, stream>>>(pairs, bbase, row_st, cnt, cntlo, dinv, csr, N, Nhalf);

    prep_kernel<<<32, 256, 0, stream>>>(W1, W2, W1T, W2T);
    mlp_mfma<<<N / 64, 256, 0, stream>>>(x, W1T, b1, W2T, b2, h, N);   // pairs dead

    hw_kernel<<<nb_n, 256, 0, stream>>>(h, cw0, nullptr, dinv, hws, N, 0);
    gather_kernel<<<nb_g, 256, 0, stream>>>(hws, dinv, csr, row_st, cnt, cntlo, agg, N, Nhalf, 0); // h dead
    gather_kernel<<<nb_g, 256, 0, stream>>>(hws, dinv, csr, row_st, cnt, cntlo, agg, N, Nhalf, 1);

    hw_kernel<<<nb_n, 256, 0, stream>>>(agg, cw1, cb0, dinv, hws, N, 1);
    gather_kernel<<<nb_g, 256, 0, stream>>>(hws, dinv, csr, row_st, cnt, cntlo, agg, N, Nhalf, 0);
    gather_kernel<<<nb_g, 256, 0, stream>>>(hws, dinv, csr, row_st, cnt, cntlo, agg, N, Nhalf, 1);

    final_kernel<<<nb_n, 256, 0, stream>>>(agg, cb1, pw, pb, out, hout, N);
}

// Round 4
// 557.855 us; speedup vs baseline: 1.2217x; 1.0566x over previous
//
#include <hip/hip_runtime.h>

// NodeGNN: h = lrelu(lrelu(x@W1+b1)@W2+b2); 2x GCNConv(16->16) over E=6.4M edges
// + self loops with symmetric norm; out = sum(h@pw+pb, -1). Returns (out[N], h[N,16]).
//
// R8: (a) gather back to ONE full-table pass per layer with dinv folded into the
// bf16 rows — R5/R6/R7 showed gather time is invariant to L2 residency (wall is
// per-CU random-transaction rate ~4.4-8.7 cyc/tx), so minimize transactions/edge
// (=1) and maximize in-flight accesses (unroll 8). (b) mlp_mfma occupancy: union
// xbf with h1s in one 34.3KB LDS buffer (xbf dead after af-fragment load; extra
// barrier protects overlay) -> 4 blocks/CU, and h1s stride 264->268 ushorts which
// makes epilogue writes bank-conflict-free (was 4-way, 1.2M conflicts) while
// keeping b128 reads at free 2-way.

#define NEG 0.01f
#define SHIFT 9                 // 512 nodes per bucket
#define BNODES (1 << SHIFT)
#define BMAX 512                // max buckets (N <= 262144)
#define PCHUNK 8192             // edges per partition block
#define H1S 268                 // h1s row stride (ushorts): 134 dw == 6 mod 8 -> cf writes

typedef __attribute__((ext_vector_type(8))) short short8;
typedef __attribute__((ext_vector_type(4))) float floatx4;
typedef __attribute__((ext_vector_type(2))) float floatx2;
typedef __attribute__((ext_vector_type(4))) unsigned short us4;
typedef __attribute__((ext_vector_type(8))) unsigned short us8;

__device__ __forceinline__ float lrelu(float v) { return v >= 0.0f ? v : NEG * v; }

__device__ __forceinline__ unsigned short f2bf(float f) {
    unsigned int u = __float_as_uint(f);
    u += 0x7fffu + ((u >> 16) & 1u);          // round-to-nearest-even
    return (unsigned short)(u >> 16);
}
__device__ __forceinline__ float bflo(unsigned int u) { return __uint_as_float(u << 16); }
__device__ __forceinline__ float bfhi(unsigned int u) { return __uint_as_float(u & 0xffff0000u); }

// ---------------------------------------------------------------------------
// K-prep: bf16-transposed weights. W1T[n][k] = bf16(W1[k][n]) (256x128),
// W2T[c][k] = bf16(W2[k][c]) (16x256).
// ---------------------------------------------------------------------------
__global__ void prep_kernel(const float* __restrict__ W1, const float* __restrict__ W2,
                            unsigned short* __restrict__ W1T, unsigned short* __restrict__ W2T)
{
    const int idx = blockIdx.x * 256 + threadIdx.x;
    const int stride = gridDim.x * 256;
    for (int i = idx; i < 256 * 128; i += stride) {
        int n = i >> 7, k = i & 127;
        W1T[i] = f2bf(W1[k * 256 + n]);
    }
    for (int i = idx; i < 16 * 256; i += stride) {
        int c = i >> 8, k = i & 255;
        W2T[i] = f2bf(W2[k * 16 + c]);
    }
}

// ---------------------------------------------------------------------------
// K1: MFMA MLP. Block = 256 threads (4 waves), 64 nodes/block.
// LDS: single 34.3KB buffer; xbf[64][136] overlays h1s[64][H1S] (xbf is dead
// once af fragments are in registers; barrier 2 protects the overlay).
// ---------------------------------------------------------------------------
__global__ __launch_bounds__(256, 4) void mlp_mfma(
    const float* __restrict__ x, const unsigned short* __restrict__ W1T,
    const float* __restrict__ b1, const unsigned short* __restrict__ W2T,
    const float* __restrict__ b2, float* __restrict__ h, int N)
{
    __shared__ unsigned short lds[64 * H1S];   // 34.3 KB
    unsigned short (*xbf)[136] = (unsigned short (*)[136])lds;
    unsigned short (*h1s)[H1S] = (unsigned short (*)[H1S])lds;

    const int tid  = threadIdx.x;
    const int n0   = blockIdx.x * 64;
    const int lane = tid & 63;
    const int lr   = lane & 15;
    const int quad = lane >> 4;
    const int wv   = tid >> 6;

    {
        const float4* xg = (const float4*)(x + (size_t)n0 * 128);
#pragma unroll
        for (int i = 0; i < 8; ++i) {
            int f = tid + 256 * i;
            float4 v = xg[f];
            int r = f >> 5, c = (f & 31) * 4;
            us4 p;
            p.x = f2bf(v.x); p.y = f2bf(v.y); p.z = f2bf(v.z); p.w = f2bf(v.w);
            *(us4*)&xbf[r][c] = p;
        }
    }
    __syncthreads();

    short8 af[4][4];
#pragma unroll
    for (int m = 0; m < 4; ++m)
#pragma unroll
        for (int kt = 0; kt < 4; ++kt)
            af[m][kt] = *(const short8*)&xbf[m * 16 + lr][kt * 32 + quad * 8];
    __syncthreads();          // xbf fully consumed; h1s may now overwrite it

    floatx4 acc[4][4];
#pragma unroll
    for (int n = 0; n < 4; ++n)
#pragma unroll
        for (int m = 0; m < 4; ++m)
            acc[n][m] = (floatx4){0.f, 0.f, 0.f, 0.f};

    const int nbase = wv * 64;
#pragma unroll
    for (int n = 0; n < 4; ++n) {
        const unsigned short* bp = &W1T[(size_t)(nbase + n * 16 + lr) * 128 + quad * 8];
        short8 bfr[4];
#pragma unroll
        for (int kt = 0; kt < 4; ++kt) bfr[kt] = *(const short8*)(bp + kt * 32);
#pragma unroll
        for (int kt = 0; kt < 4; ++kt)
#pragma unroll
            for (int m = 0; m < 4; ++m)
                acc[n][m] = __builtin_amdgcn_mfma_f32_16x16x32_bf16(
                    af[m][kt], bfr[kt], acc[n][m], 0, 0, 0);
    }

#pragma unroll
    for (int n = 0; n < 4; ++n) {
        float bc = b1[nbase + n * 16 + lr];
#pragma unroll
        for (int m = 0; m < 4; ++m)
#pragma unroll
            for (int reg = 0; reg < 4; ++reg) {
                float v = lrelu(acc[n][m][reg] + bc);
                h1s[m * 16 + quad * 4 + reg][nbase + n * 16 + lr] = f2bf(v);
            }
    }
    __syncthreads();

    floatx4 acc2 = (floatx4){0.f, 0.f, 0.f, 0.f};
#pragma unroll
    for (int kt = 0; kt < 8; ++kt) {
        short8 a2 = *(const short8*)&h1s[wv * 16 + lr][kt * 32 + quad * 8];
        short8 b2f = *(const short8*)&W2T[lr * 256 + kt * 32 + quad * 8];
        acc2 = __builtin_amdgcn_mfma_f32_16x16x32_bf16(a2, b2f, acc2, 0, 0, 0);
    }
    float bb = b2[lr];
#pragma unroll
    for (int reg = 0; reg < 4; ++reg) {
        int r = n0 + wv * 16 + quad * 4 + reg;
        h[(size_t)r * 16 + lr] = lrelu(acc2[reg] + bb);
    }
}

// ---------------------------------------------------------------------------
// K0: zero the global bucket counters
// ---------------------------------------------------------------------------
__global__ void zero_kernel(int* __restrict__ bcnt)
{
    bcnt[threadIdx.x] = 0;
}

// ---------------------------------------------------------------------------
// K2: per-bucket edge histogram (LDS-aggregated)
// ---------------------------------------------------------------------------
__global__ __launch_bounds__(256) void bucket_count(
    const int* __restrict__ eidx, int* __restrict__ bcnt, int E, int N, int B)
{
    __shared__ int hist[BMAX];
    const int t = threadIdx.x;
    for (int b = t; b < B; b += 256) hist[b] = 0;
    __syncthreads();

    const int stride = gridDim.x * 256;
    for (int e = blockIdx.x * 256 + t; e < E; e += stride) {
        int d = eidx[E + e];
        d = min(max(d, 0), N - 1);
        atomicAdd(&hist[d >> SHIFT], 1);
    }
    __syncthreads();
    for (int b = t; b < B; b += 256) {
        int c = hist[b];
        if (c) atomicAdd(&bcnt[b], c);
    }
}

// ---------------------------------------------------------------------------
// K3: single-block exclusive scan over bucket counts
// ---------------------------------------------------------------------------
__global__ __launch_bounds__(512) void scan_kernel(
    const int* __restrict__ bcnt, int* __restrict__ bbase, int* __restrict__ gcur, int B)
{
    __shared__ int s[BMAX];
    const int t = threadIdx.x;        // 512 threads
    int c = (t < B) ? bcnt[t] : 0;
    s[t] = c;
    __syncthreads();
#pragma unroll
    for (int off = 1; off < BMAX; off <<= 1) {
        int v = s[t];
        int u = (t >= off) ? s[t - off] : 0;
        __syncthreads();
        s[t] = v + u;
        __syncthreads();
    }
    if (t < B) {
        int excl = s[t] - c;
        bbase[t] = excl;
        gcur[t]  = excl;
    }
    if (t == 0) bbase[B] = s[BMAX - 1];
}

// ---------------------------------------------------------------------------
// K4: partition via block-level LDS counting sort + coalesced run flush.
// ---------------------------------------------------------------------------
__global__ __launch_bounds__(512) void partition_kernel(
    const int* __restrict__ eidx, int* __restrict__ gcur, int* __restrict__ pairs,
    int E, int N, int B)
{
    __shared__ int hist[BMAX];        // count -> cursor
    __shared__ int offx[BMAX + 1];    // exclusive local offsets (kept intact)
    __shared__ int basec[BMAX];       // global run base for this block
    __shared__ int sorted[PCHUNK];    // 32KB; doubles as scan scratch
    const int t  = threadIdx.x;
    const int e0 = blockIdx.x * PCHUNK;
    const int elim = min(PCHUNK, E - e0);

    hist[t] = 0;
    __syncthreads();
    for (int i = t; i < elim; i += 512) {
        int d = eidx[E + e0 + i];
        d = min(max(d, 0), N - 1);
        atomicAdd(&hist[d >> SHIFT], 1);
    }
    __syncthreads();

    int c = hist[t];
    sorted[t] = c;
    __syncthreads();
#pragma unroll
    for (int o = 1; o < BMAX; o <<= 1) {
        int v = sorted[t];
        int u = (t >= o) ? sorted[t - o] : 0;
        __syncthreads();
        sorted[t] = v + u;
        __syncthreads();
    }
    const int excl = sorted[t] - c;
    offx[t] = excl;
    if (t == 0) offx[BMAX] = elim;
    basec[t] = (t < B && c) ? atomicAdd(&gcur[t], c) : 0;
    hist[t] = excl;                   // becomes local cursor
    __syncthreads();

    for (int i = t; i < elim; i += 512) {
        int s = eidx[e0 + i];
        int d = eidx[E + e0 + i];
        s = min(max(s, 0), N - 1);
        d = min(max(d, 0), N - 1);
        int b = d >> SHIFT;
        int p = atomicAdd(&hist[b], 1);
        sorted[p] = (s << SHIFT) | (d & (BNODES - 1));
    }
    __syncthreads();

    for (int slot = t; slot < elim; slot += 512) {
        int v = sorted[slot];
        int l = 0, r = BMAX - 1;
#pragma unroll
        for (int it = 0; it < 9; ++it) {
            int m = (l + r + 1) >> 1;
            if (offx[m] <= slot) l = m; else r = m - 1;
        }
        pairs[basec[l] + (slot - offx[l])] = v;
    }
}

// ---------------------------------------------------------------------------
// K5: per-bucket counting sort -> csr, plus row_start/cnt/dinv
// ---------------------------------------------------------------------------
__global__ __launch_bounds__(512) void build_csr(
    const int* __restrict__ pairs, const int* __restrict__ bbase,
    int* __restrict__ row_start, int* __restrict__ cnt_out, float* __restrict__ dinv,
    int* __restrict__ csr, int N)
{
    __shared__ int cnt[BNODES];
    __shared__ int off[BNODES];
    const int b = blockIdx.x, t = threadIdx.x;   // 512 threads
    const int node0 = b << SHIFT;
    const int lo = bbase[b], hi = bbase[b + 1];

    cnt[t] = 0;
    __syncthreads();
    for (int e = lo + t; e < hi; e += 512)
        atomicAdd(&cnt[pairs[e] & (BNODES - 1)], 1);
    __syncthreads();

    int c = cnt[t];
    off[t] = c;
    __syncthreads();
#pragma unroll
    for (int o = 1; o < BNODES; o <<= 1) {
        int v = off[t];
        int u = (t >= o) ? off[t - o] : 0;
        __syncthreads();
        off[t] = v + u;
        __syncthreads();
    }
    const int excl = off[t] - c;
    const int node = node0 + t;
    if (node < N) {
        row_start[node] = lo + excl;
        cnt_out[node]   = c;
        dinv[node]      = rsqrtf((float)(c + 1));
    }
    cnt[t] = lo + excl;              // reuse as cursor
    __syncthreads();
    for (int e = lo + t; e < hi; e += 512) {
        int v = pairs[e];
        int p = atomicAdd(&cnt[v & (BNODES - 1)], 1);
        csr[p] = v >> SHIFT;
    }
}

// ---------------------------------------------------------------------------
// K6: hw = (optionally lrelu(in + bias_prev)) @ W[16x16], scaled by dinv[i],
// stored as bf16 rows (32B/row): 1 random transaction per edge in the gather.
// ---------------------------------------------------------------------------
__global__ void hw_kernel(const float* __restrict__ in, const float* __restrict__ W,
                          const float* __restrict__ bias, const float* __restrict__ dinv,
                          unsigned short* __restrict__ out, int N, int apply)
{
    int i = blockIdx.x * 256 + threadIdx.x;
    if (i >= N) return;
    const float4* ir = (const float4*)(in + (size_t)i * 16);
    float4 r0 = ir[0], r1 = ir[1], r2 = ir[2], r3 = ir[3];
    float v[16] = {r0.x, r0.y, r0.z, r0.w, r1.x, r1.y, r1.z, r1.w,
                   r2.x, r2.y, r2.z, r2.w, r3.x, r3.y, r3.z, r3.w};
    if (apply) {
#pragma unroll
        for (int c = 0; c < 16; ++c) v[c] = lrelu(v[c] + bias[c]);
    }
    float o[16];
#pragma unroll
    for (int c = 0; c < 16; ++c) o[c] = 0.0f;
#pragma unroll
    for (int k = 0; k < 16; ++k) {
        float vk = v[k];
#pragma unroll
        for (int c = 0; c < 16; ++c) o[c] += vk * W[k * 16 + c];
    }
    float ds = dinv[i];
    us8 lo8, hi8;
#pragma unroll
    for (int c = 0; c < 8; ++c) { lo8[c] = f2bf(o[c] * ds); hi8[c] = f2bf(o[c + 8] * ds); }
    us8* orow = (us8*)(out + (size_t)i * 16);
    orow[0] = lo8;
    orow[1] = hi8;
}

// ---------------------------------------------------------------------------
// K7: gather over bf16 rows pre-scaled by dinv_src. 8 lanes/node, lane cp owns
// features 2cp,2cp+1 (one uint). Single pass over the full table: residency
// doesn't matter (tx-rate wall); minimize transactions (1/edge) and keep 8
// row-loads in flight per lane via unroll-8 with batched index loads.
// agg[d] = dinv_d * (row_d + sum_src row_src)
// ---------------------------------------------------------------------------
__global__ __launch_bounds__(256) void gather_kernel(
    const unsigned short* __restrict__ hws, const float* __restrict__ dinv,
    const int* __restrict__ csr, const int* __restrict__ row_start,
    const int* __restrict__ cnt, float* __restrict__ agg, int N)
{
    int t    = blockIdx.x * 256 + threadIdx.x;
    int node = t >> 3;
    int cp   = t & 7;
    if (node >= N) return;

    const unsigned int* rows = (const unsigned int*)hws;   // row i = 8 uints

    int   s0 = row_start[node];
    int   n  = cnt[node];
    float di = dinv[node];
    unsigned int self = rows[(size_t)node * 8 + cp];
    float a0 = bflo(self), a1 = bfhi(self);

    int j = 0;
    for (; j + 8 <= n; j += 8) {
        int s[8];
#pragma unroll
        for (int u = 0; u < 8; ++u) s[u] = __builtin_nontemporal_load(&csr[s0 + j + u]);
        unsigned int v[8];
#pragma unroll
        for (int u = 0; u < 8; ++u) v[u] = rows[(size_t)s[u] * 8 + cp];
#pragma unroll
        for (int u = 0; u < 8; ++u) { a0 += bflo(v[u]); a1 += bfhi(v[u]); }
    }
    for (; j < n; ++j) {
        int s = __builtin_nontemporal_load(&csr[s0 + j]);
        unsigned int v = rows[(size_t)s * 8 + cp];
        a0 += bflo(v); a1 += bfhi(v);
    }

    floatx2 r;
    r.x = a0 * di; r.y = a1 * di;
    __builtin_nontemporal_store(r, (floatx2*)&agg[(size_t)node * 16 + cp * 2]);
}

// ---------------------------------------------------------------------------
// K8: final head. h = lrelu(agg + cb1); out = h . (pw[:,0]+pw[:,1]) + pb0+pb1
// ---------------------------------------------------------------------------
__global__ void final_kernel(const float* __restrict__ agg, const float* __restrict__ cb1,
                             const float* __restrict__ pw, const float* __restrict__ pb,
                             float* __restrict__ out, float* __restrict__ hout, int N)
{
    int i = blockIdx.x * 256 + threadIdx.x;
    if (i >= N) return;
    const float4* ar = (const float4*)(agg + (size_t)i * 16);
    float4 r0 = ar[0], r1 = ar[1], r2 = ar[2], r3 = ar[3];
    float v[16] = {r0.x, r0.y, r0.z, r0.w, r1.x, r1.y, r1.z, r1.w,
                   r2.x, r2.y, r2.z, r2.w, r3.x, r3.y, r3.z, r3.w};
    float s = pb[0] + pb[1];
#pragma unroll
    for (int c = 0; c < 16; ++c) {
        v[c] = lrelu(v[c] + cb1[c]);
        s += v[c] * (pw[c * 2] + pw[c * 2 + 1]);
    }
    out[i] = s;
    float4* hr = (float4*)(hout + (size_t)i * 16);
    hr[0] = make_float4(v[0],  v[1],  v[2],  v[3]);
    hr[1] = make_float4(v[4],  v[5],  v[6],  v[7]);
    hr[2] = make_float4(v[8],  v[9],  v[10], v[11]);
    hr[3] = make_float4(v[12], v[13], v[14], v[15]);
}

// ---------------------------------------------------------------------------
extern "C" void kernel_launch(void* const* d_in, const int* in_sizes, int n_in,
                              void* d_out, int out_size, void* d_ws, size_t ws_size,
                              hipStream_t stream)
{
    const float* x   = (const float*)d_in[0];
    const float* W1  = (const float*)d_in[1];
    const float* b1  = (const float*)d_in[2];
    const float* W2  = (const float*)d_in[3];
    const float* b2  = (const float*)d_in[4];
    const float* cw0 = (const float*)d_in[5];
    const float* cb0 = (const float*)d_in[6];
    const float* cw1 = (const float*)d_in[7];
    const float* cb1 = (const float*)d_in[8];
    const float* pw  = (const float*)d_in[9];
    const float* pb  = (const float*)d_in[10];
    const int*   eidx = (const int*)d_in[11];

    const int N = in_sizes[0] / 128;
    const int E = in_sizes[11] / 2;
    const int B = (N + BNODES - 1) >> SHIFT;

    // workspace carve-out (~61 MB); X region serves pairs -> h -> agg
    char* w = (char*)d_ws;
    unsigned short* hws = (unsigned short*)w; w += (size_t)N * 16 * 2;  // bf16 rows (32B)
    float* dinv    = (float*)w; w += (size_t)N * 4;
    int*   cnt     = (int*)w;   w += (size_t)N * 4;
    int*   row_st  = (int*)w;   w += (size_t)N * 4;
    int*   csr     = (int*)w;   w += (size_t)E * 4;
    char*  X       = w;         w += (size_t)E * 4;
    int*   bcnt    = (int*)w;   w += BMAX * 4;
    int*   bbase   = (int*)w;   w += (BMAX + 4) * 4;   // +4 keeps 16B alignment below
    int*   gcur    = (int*)w;   w += BMAX * 4;
    unsigned short* W1T = (unsigned short*)w; w += 256 * 128 * 2;  // 16B-aligned
    unsigned short* W2T = (unsigned short*)w; w += 16 * 256 * 2;

    int*   pairs = (int*)X;     // live: partition -> build_csr
    float* h     = (float*)X;   // live: mlp -> hw1 (pairs dead)
    float* agg   = (float*)X;   // live: gather -> final (h dead)

    float* out  = (float*)d_out;
    float* hout = out + N;

    const int nb_n = (N + 255) / 256;
    const int nb_g = (N * 8 + 255) / 256;
    const int nb_p = (E + PCHUNK - 1) / PCHUNK;

    // CSR chain first so dinv exists before hw_kernel folds it into the rows.
    zero_kernel<<<1, BMAX, 0, stream>>>(bcnt);
    bucket_count<<<1024, 256, 0, stream>>>(eidx, bcnt, E, N, B);
    scan_kernel<<<1, BMAX, 0, stream>>>(bcnt, bbase, gcur, B);
    partition_kernel<<<nb_p, 512, 0, stream>>>(eidx, gcur, pairs, E, N, B);
    build_csr<<<B, 512, 0, stream>>>(pairs, bbase, row_st, cnt, dinv, csr, N);

    prep_kernel<<<32, 256, 0, stream>>>(W1, W2, W1T, W2T);
    mlp_mfma<<<N / 64, 256, 0, stream>>>(x, W1T, b1, W2T, b2, h, N);   // pairs dead

    hw_kernel<<<nb_n, 256, 0, stream>>>(h, cw0, nullptr, dinv, hws, N, 0);
    gather_kernel<<<nb_g, 256, 0, stream>>>(hws, dinv, csr, row_st, cnt, agg, N); // h dead

    hw_kernel<<<nb_n, 256, 0, stream>>>(agg, cw1, cb0, dinv, hws, N, 1);
    gather_kernel<<<nb_g, 256, 0, stream>>>(hws, dinv, csr, row_st, cnt, agg, N);

    final_kernel<<<nb_n, 256, 0, stream>>>(agg, cb1, pw, pb, out, hout, N);
}

// Round 5
// 507.816 us; speedup vs baseline: 1.3420x; 1.0985x over previous
//
#include <hip/hip_runtime.h>

// NodeGNN: h = lrelu(lrelu(x@W1+b1)@W2+b2); 2x GCNConv(16->16) over E=6.4M edges
// + self loops with symmetric norm; out = sum(h@pw+pb, -1). Returns (out[N], h[N,16]).
//
// R9: the gathers are at the measured divergent-access floor (~8 cyc per random
// 32B tx per CU, invariant across R4-R8 configs). Attack the hidden ~315us:
// (a) build_csr's csr[p] scatter was 6.4M random 4B global stores (same tx floor,
//     est 40-80us) -> counting-sort into LDS (75KB, 2 blocks/CU) + coalesced flush.
// (b) fuse hw2 into gather1's epilogue (8-lane shuffle-rotation 16x16 matmul,
//     weights in LDS) and the final head into gather2 (shfl_xor tree reduce):
//     -2 launches, -51MB agg round-trip; layer-2 rows go into the free X region.

#define NEG 0.01f
#define SHIFT 9                 // 512 nodes per bucket
#define BNODES (1 << SHIFT)
#define BMAX 512                // max buckets (N <= 262144)
#define PCHUNK 8192             // edges per partition block
#define H1S 268                 // h1s row stride (ushorts): cf epilogue writes
#define CSRCAP 19200            // LDS-staged bucket sort capacity (mean 16.4K +22sigma)

typedef __attribute__((ext_vector_type(8))) short short8;
typedef __attribute__((ext_vector_type(4))) float floatx4;
typedef __attribute__((ext_vector_type(2))) float floatx2;
typedef __attribute__((ext_vector_type(4))) unsigned short us4;
typedef __attribute__((ext_vector_type(8))) unsigned short us8;

__device__ __forceinline__ float lrelu(float v) { return v >= 0.0f ? v : NEG * v; }

__device__ __forceinline__ unsigned short f2bf(float f) {
    unsigned int u = __float_as_uint(f);
    u += 0x7fffu + ((u >> 16) & 1u);          // round-to-nearest-even
    return (unsigned short)(u >> 16);
}
__device__ __forceinline__ float bflo(unsigned int u) { return __uint_as_float(u << 16); }
__device__ __forceinline__ float bfhi(unsigned int u) { return __uint_as_float(u & 0xffff0000u); }

// ---------------------------------------------------------------------------
// K-prep: bf16-transposed weights. W1T[n][k] = bf16(W1[k][n]) (256x128),
// W2T[c][k] = bf16(W2[k][c]) (16x256).
// ---------------------------------------------------------------------------
__global__ void prep_kernel(const float* __restrict__ W1, const float* __restrict__ W2,
                            unsigned short* __restrict__ W1T, unsigned short* __restrict__ W2T)
{
    const int idx = blockIdx.x * 256 + threadIdx.x;
    const int stride = gridDim.x * 256;
    for (int i = idx; i < 256 * 128; i += stride) {
        int n = i >> 7, k = i & 127;
        W1T[i] = f2bf(W1[k * 256 + n]);
    }
    for (int i = idx; i < 16 * 256; i += stride) {
        int c = i >> 8, k = i & 255;
        W2T[i] = f2bf(W2[k * 16 + c]);
    }
}

// ---------------------------------------------------------------------------
// K1: MFMA MLP. Block = 256 threads (4 waves), 64 nodes/block. (unchanged R8)
// ---------------------------------------------------------------------------
__global__ __launch_bounds__(256, 4) void mlp_mfma(
    const float* __restrict__ x, const unsigned short* __restrict__ W1T,
    const float* __restrict__ b1, const unsigned short* __restrict__ W2T,
    const float* __restrict__ b2, float* __restrict__ h, int N)
{
    __shared__ unsigned short lds[64 * H1S];   // 34.3 KB
    unsigned short (*xbf)[136] = (unsigned short (*)[136])lds;
    unsigned short (*h1s)[H1S] = (unsigned short (*)[H1S])lds;

    const int tid  = threadIdx.x;
    const int n0   = blockIdx.x * 64;
    const int lane = tid & 63;
    const int lr   = lane & 15;
    const int quad = lane >> 4;
    const int wv   = tid >> 6;

    {
        const float4* xg = (const float4*)(x + (size_t)n0 * 128);
#pragma unroll
        for (int i = 0; i < 8; ++i) {
            int f = tid + 256 * i;
            float4 v = xg[f];
            int r = f >> 5, c = (f & 31) * 4;
            us4 p;
            p.x = f2bf(v.x); p.y = f2bf(v.y); p.z = f2bf(v.z); p.w = f2bf(v.w);
            *(us4*)&xbf[r][c] = p;
        }
    }
    __syncthreads();

    short8 af[4][4];
#pragma unroll
    for (int m = 0; m < 4; ++m)
#pragma unroll
        for (int kt = 0; kt < 4; ++kt)
            af[m][kt] = *(const short8*)&xbf[m * 16 + lr][kt * 32 + quad * 8];
    __syncthreads();          // xbf fully consumed; h1s may now overwrite it

    floatx4 acc[4][4];
#pragma unroll
    for (int n = 0; n < 4; ++n)
#pragma unroll
        for (int m = 0; m < 4; ++m)
            acc[n][m] = (floatx4){0.f, 0.f, 0.f, 0.f};

    const int nbase = wv * 64;
#pragma unroll
    for (int n = 0; n < 4; ++n) {
        const unsigned short* bp = &W1T[(size_t)(nbase + n * 16 + lr) * 128 + quad * 8];
        short8 bfr[4];
#pragma unroll
        for (int kt = 0; kt < 4; ++kt) bfr[kt] = *(const short8*)(bp + kt * 32);
#pragma unroll
        for (int kt = 0; kt < 4; ++kt)
#pragma unroll
            for (int m = 0; m < 4; ++m)
                acc[n][m] = __builtin_amdgcn_mfma_f32_16x16x32_bf16(
                    af[m][kt], bfr[kt], acc[n][m], 0, 0, 0);
    }

#pragma unroll
    for (int n = 0; n < 4; ++n) {
        float bc = b1[nbase + n * 16 + lr];
#pragma unroll
        for (int m = 0; m < 4; ++m)
#pragma unroll
            for (int reg = 0; reg < 4; ++reg) {
                float v = lrelu(acc[n][m][reg] + bc);
                h1s[m * 16 + quad * 4 + reg][nbase + n * 16 + lr] = f2bf(v);
            }
    }
    __syncthreads();

    floatx4 acc2 = (floatx4){0.f, 0.f, 0.f, 0.f};
#pragma unroll
    for (int kt = 0; kt < 8; ++kt) {
        short8 a2 = *(const short8*)&h1s[wv * 16 + lr][kt * 32 + quad * 8];
        short8 b2f = *(const short8*)&W2T[lr * 256 + kt * 32 + quad * 8];
        acc2 = __builtin_amdgcn_mfma_f32_16x16x32_bf16(a2, b2f, acc2, 0, 0, 0);
    }
    float bb = b2[lr];
#pragma unroll
    for (int reg = 0; reg < 4; ++reg) {
        int r = n0 + wv * 16 + quad * 4 + reg;
        h[(size_t)r * 16 + lr] = lrelu(acc2[reg] + bb);
    }
}

// ---------------------------------------------------------------------------
// K0: zero the global bucket counters
// ---------------------------------------------------------------------------
__global__ void zero_kernel(int* __restrict__ bcnt)
{
    bcnt[threadIdx.x] = 0;
}

// ---------------------------------------------------------------------------
// K2: per-bucket edge histogram (LDS-aggregated)
// ---------------------------------------------------------------------------
__global__ __launch_bounds__(256) void bucket_count(
    const int* __restrict__ eidx, int* __restrict__ bcnt, int E, int N, int B)
{
    __shared__ int hist[BMAX];
    const int t = threadIdx.x;
    for (int b = t; b < B; b += 256) hist[b] = 0;
    __syncthreads();

    const int stride = gridDim.x * 256;
    for (int e = blockIdx.x * 256 + t; e < E; e += stride) {
        int d = eidx[E + e];
        d = min(max(d, 0), N - 1);
        atomicAdd(&hist[d >> SHIFT], 1);
    }
    __syncthreads();
    for (int b = t; b < B; b += 256) {
        int c = hist[b];
        if (c) atomicAdd(&bcnt[b], c);
    }
}

// ---------------------------------------------------------------------------
// K3: single-block exclusive scan over bucket counts
// ---------------------------------------------------------------------------
__global__ __launch_bounds__(512) void scan_kernel(
    const int* __restrict__ bcnt, int* __restrict__ bbase, int* __restrict__ gcur, int B)
{
    __shared__ int s[BMAX];
    const int t = threadIdx.x;        // 512 threads
    int c = (t < B) ? bcnt[t] : 0;
    s[t] = c;
    __syncthreads();
#pragma unroll
    for (int off = 1; off < BMAX; off <<= 1) {
        int v = s[t];
        int u = (t >= off) ? s[t - off] : 0;
        __syncthreads();
        s[t] = v + u;
        __syncthreads();
    }
    if (t < B) {
        int excl = s[t] - c;
        bbase[t] = excl;
        gcur[t]  = excl;
    }
    if (t == 0) bbase[B] = s[BMAX - 1];
}

// ---------------------------------------------------------------------------
// K4: partition via block-level LDS counting sort + coalesced run flush.
// ---------------------------------------------------------------------------
__global__ __launch_bounds__(512) void partition_kernel(
    const int* __restrict__ eidx, int* __restrict__ gcur, int* __restrict__ pairs,
    int E, int N, int B)
{
    __shared__ int hist[BMAX];        // count -> cursor
    __shared__ int offx[BMAX + 1];    // exclusive local offsets (kept intact)
    __shared__ int basec[BMAX];       // global run base for this block
    __shared__ int sorted[PCHUNK];    // 32KB; doubles as scan scratch
    const int t  = threadIdx.x;
    const int e0 = blockIdx.x * PCHUNK;
    const int elim = min(PCHUNK, E - e0);

    hist[t] = 0;
    __syncthreads();
    for (int i = t; i < elim; i += 512) {
        int d = eidx[E + e0 + i];
        d = min(max(d, 0), N - 1);
        atomicAdd(&hist[d >> SHIFT], 1);
    }
    __syncthreads();

    int c = hist[t];
    sorted[t] = c;
    __syncthreads();
#pragma unroll
    for (int o = 1; o < BMAX; o <<= 1) {
        int v = sorted[t];
        int u = (t >= o) ? sorted[t - o] : 0;
        __syncthreads();
        sorted[t] = v + u;
        __syncthreads();
    }
    const int excl = sorted[t] - c;
    offx[t] = excl;
    if (t == 0) offx[BMAX] = elim;
    basec[t] = (t < B && c) ? atomicAdd(&gcur[t], c) : 0;
    hist[t] = excl;                   // becomes local cursor
    __syncthreads();

    for (int i = t; i < elim; i += 512) {
        int s = eidx[e0 + i];
        int d = eidx[E + e0 + i];
        s = min(max(s, 0), N - 1);
        d = min(max(d, 0), N - 1);
        int b = d >> SHIFT;
        int p = atomicAdd(&hist[b], 1);
        sorted[p] = (s << SHIFT) | (d & (BNODES - 1));
    }
    __syncthreads();

    for (int slot = t; slot < elim; slot += 512) {
        int v = sorted[slot];
        int l = 0, r = BMAX - 1;
#pragma unroll
        for (int it = 0; it < 9; ++it) {
            int m = (l + r + 1) >> 1;
            if (offx[m] <= slot) l = m; else r = m - 1;
        }
        pairs[basec[l] + (slot - offx[l])] = v;
    }
}

// ---------------------------------------------------------------------------
// K5: per-bucket counting sort -> csr, plus row_start/cnt/dinv.
// R9: sort lands in LDS (75KB) and flushes to csr COALESCED — the old direct
// csr[p] scatter was 6.4M random 4B global stores (divergent-tx floor).
// ---------------------------------------------------------------------------
__global__ __launch_bounds__(512) void build_csr(
    const int* __restrict__ pairs, const int* __restrict__ bbase,
    int* __restrict__ row_start, int* __restrict__ cnt_out, float* __restrict__ dinv,
    int* __restrict__ csr, int N)
{
    __shared__ int cnt[BNODES];
    __shared__ int off[BNODES];
    __shared__ int sorted[CSRCAP];               // 75 KB -> 79 KB total, 2 blocks/CU
    const int b = blockIdx.x, t = threadIdx.x;   // 512 threads
    const int node0 = b << SHIFT;
    const int lo = bbase[b], hi = bbase[b + 1];
    const int m = hi - lo;
    const bool fits = (m <= CSRCAP);             // statistically always true

    cnt[t] = 0;
    __syncthreads();
    for (int e = lo + t; e < hi; e += 512)
        atomicAdd(&cnt[pairs[e] & (BNODES - 1)], 1);
    __syncthreads();

    int c = cnt[t];
    off[t] = c;
    __syncthreads();
#pragma unroll
    for (int o = 1; o < BNODES; o <<= 1) {
        int v = off[t];
        int u = (t >= o) ? off[t - o] : 0;
        __syncthreads();
        off[t] = v + u;
        __syncthreads();
    }
    const int excl = off[t] - c;
    const int node = node0 + t;
    if (node < N) {
        row_start[node] = lo + excl;
        cnt_out[node]   = c;
        dinv[node]      = rsqrtf((float)(c + 1));
    }
    cnt[t] = excl;                   // local (0-based) cursor
    __syncthreads();
    for (int e = lo + t; e < hi; e += 512) {
        int v = pairs[e];
        int p = atomicAdd(&cnt[v & (BNODES - 1)], 1);
        int s = v >> SHIFT;
        if (fits) sorted[p] = s;
        else      csr[lo + p] = s;   // fallback (never statistically)
    }
    __syncthreads();
    if (fits)
        for (int i = t; i < m; i += 512)
            csr[lo + i] = sorted[i]; // coalesced flush
}

// ---------------------------------------------------------------------------
// K6: hw = in @ W[16x16] scaled by dinv[i], stored as bf16 rows (32B/row).
// Used for layer 1 only (layer 2's hw is fused into gather_hw).
// ---------------------------------------------------------------------------
__global__ void hw_kernel(const float* __restrict__ in, const float* __restrict__ W,
                          const float* __restrict__ dinv,
                          unsigned short* __restrict__ out, int N)
{
    int i = blockIdx.x * 256 + threadIdx.x;
    if (i >= N) return;
    const float4* ir = (const float4*)(in + (size_t)i * 16);
    float4 r0 = ir[0], r1 = ir[1], r2 = ir[2], r3 = ir[3];
    float v[16] = {r0.x, r0.y, r0.z, r0.w, r1.x, r1.y, r1.z, r1.w,
                   r2.x, r2.y, r2.z, r2.w, r3.x, r3.y, r3.z, r3.w};
    float o[16];
#pragma unroll
    for (int c = 0; c < 16; ++c) o[c] = 0.0f;
#pragma unroll
    for (int k = 0; k < 16; ++k) {
        float vk = v[k];
#pragma unroll
        for (int c = 0; c < 16; ++c) o[c] += vk * W[k * 16 + c];
    }
    float ds = dinv[i];
    us8 lo8, hi8;
#pragma unroll
    for (int c = 0; c < 8; ++c) { lo8[c] = f2bf(o[c] * ds); hi8[c] = f2bf(o[c + 8] * ds); }
    us8* orow = (us8*)(out + (size_t)i * 16);
    orow[0] = lo8;
    orow[1] = hi8;
}

// ---------------------------------------------------------------------------
// K7a: layer-1 gather fused with layer-2 hw. 8 lanes/node, lane cp owns
// features 2cp,2cp+1. After the gather (rows pre-scaled by dinv_src):
//   agg = a*dinv_d; v = lrelu(agg + cb0); o = v @ cw1;  row2 = bf16(o*dinv_d)
// The 16x16 matmul runs as an 8-lane shuffle rotation with cw1 in LDS
// (broadcast reads, conflict-free).
// ---------------------------------------------------------------------------
__global__ __launch_bounds__(256) void gather_hw(
    const unsigned short* __restrict__ hws, const float* __restrict__ dinv,
    const int* __restrict__ csr, const int* __restrict__ row_start,
    const int* __restrict__ cnt, const float* __restrict__ cb0,
    const float* __restrict__ cw1, unsigned int* __restrict__ rows2, int N)
{
    __shared__ float Wl[256];
    Wl[threadIdx.x] = cw1[threadIdx.x];
    __syncthreads();

    int t    = blockIdx.x * 256 + threadIdx.x;
    int node = t >> 3;
    int cp   = t & 7;
    if (node >= N) return;

    const unsigned int* rows = (const unsigned int*)hws;   // row i = 8 uints

    int   s0 = row_start[node];
    int   n  = cnt[node];
    float di = dinv[node];
    unsigned int self = rows[(size_t)node * 8 + cp];
    float a0 = bflo(self), a1 = bfhi(self);

    int j = 0;
    for (; j + 8 <= n; j += 8) {
        int s[8];
#pragma unroll
        for (int u = 0; u < 8; ++u) s[u] = __builtin_nontemporal_load(&csr[s0 + j + u]);
        unsigned int v[8];
#pragma unroll
        for (int u = 0; u < 8; ++u) v[u] = rows[(size_t)s[u] * 8 + cp];
#pragma unroll
        for (int u = 0; u < 8; ++u) { a0 += bflo(v[u]); a1 += bfhi(v[u]); }
    }
    for (; j < n; ++j) {
        int s = __builtin_nontemporal_load(&csr[s0 + j]);
        unsigned int v = rows[(size_t)s * 8 + cp];
        a0 += bflo(v); a1 += bfhi(v);
    }

    float v0 = lrelu(a0 * di + cb0[2 * cp]);
    float v1 = lrelu(a1 * di + cb0[2 * cp + 1]);

    float o0 = 0.0f, o1 = 0.0f;
#pragma unroll
    for (int r = 0; r < 8; ++r) {
        int src = (cp + r) & 7;
        float vk0 = __shfl(v0, src, 8);
        float vk1 = __shfl(v1, src, 8);
        floatx2 wa = *(const floatx2*)&Wl[(2 * src) * 16 + 2 * cp];
        floatx2 wb = *(const floatx2*)&Wl[(2 * src + 1) * 16 + 2 * cp];
        o0 += vk0 * wa.x + vk1 * wb.x;
        o1 += vk0 * wa.y + vk1 * wb.y;
    }
    unsigned int u = (unsigned int)f2bf(o0 * di) | ((unsigned int)f2bf(o1 * di) << 16);
    rows2[(size_t)node * 8 + cp] = u;
}

// ---------------------------------------------------------------------------
// K7b: layer-2 gather fused with the final head.
//   v = lrelu(a*dinv_d + cb1);  hout = v;  out = sum(v .* (pw0+pw1)) + pb0+pb1
// 8-lane shfl_xor tree reduces the dot product.
// ---------------------------------------------------------------------------
__global__ __launch_bounds__(256) void gather_final(
    const unsigned short* __restrict__ hws, const float* __restrict__ dinv,
    const int* __restrict__ csr, const int* __restrict__ row_start,
    const int* __restrict__ cnt, const float* __restrict__ cb1,
    const float* __restrict__ pw, const float* __restrict__ pb,
    float* __restrict__ out, float* __restrict__ hout, int N)
{
    int t    = blockIdx.x * 256 + threadIdx.x;
    int node = t >> 3;
    int cp   = t & 7;
    if (node >= N) return;

    const unsigned int* rows = (const unsigned int*)hws;   // row i = 8 uints

    int   s0 = row_start[node];
    int   n  = cnt[node];
    float di = dinv[node];
    unsigned int self = rows[(size_t)node * 8 + cp];
    float a0 = bflo(self), a1 = bfhi(self);

    int j = 0;
    for (; j + 8 <= n; j += 8) {
        int s[8];
#pragma unroll
        for (int u = 0; u < 8; ++u) s[u] = __builtin_nontemporal_load(&csr[s0 + j + u]);
        unsigned int v[8];
#pragma unroll
        for (int u = 0; u < 8; ++u) v[u] = rows[(size_t)s[u] * 8 + cp];
#pragma unroll
        for (int u = 0; u < 8; ++u) { a0 += bflo(v[u]); a1 += bfhi(v[u]); }
    }
    for (; j < n; ++j) {
        int s = __builtin_nontemporal_load(&csr[s0 + j]);
        unsigned int v = rows[(size_t)s * 8 + cp];
        a0 += bflo(v); a1 += bfhi(v);
    }

    float v0 = lrelu(a0 * di + cb1[2 * cp]);
    float v1 = lrelu(a1 * di + cb1[2 * cp + 1]);

    float s = v0 * (pw[4 * cp] + pw[4 * cp + 1]) + v1 * (pw[4 * cp + 2] + pw[4 * cp + 3]);
    s += __shfl_xor(s, 1, 8);
    s += __shfl_xor(s, 2, 8);
    s += __shfl_xor(s, 4, 8);
    if (cp == 0) out[node] = s + pb[0] + pb[1];

    floatx2 hv; hv.x = v0; hv.y = v1;
    __builtin_nontemporal_store(hv, (floatx2*)&hout[(size_t)node * 16 + 2 * cp]);
}

// ---------------------------------------------------------------------------
extern "C" void kernel_launch(void* const* d_in, const int* in_sizes, int n_in,
                              void* d_out, int out_size, void* d_ws, size_t ws_size,
                              hipStream_t stream)
{
    const float* x   = (const float*)d_in[0];
    const float* W1  = (const float*)d_in[1];
    const float* b1  = (const float*)d_in[2];
    const float* W2  = (const float*)d_in[3];
    const float* b2  = (const float*)d_in[4];
    const float* cw0 = (const float*)d_in[5];
    const float* cb0 = (const float*)d_in[6];
    const float* cw1 = (const float*)d_in[7];
    const float* cb1 = (const float*)d_in[8];
    const float* pw  = (const float*)d_in[9];
    const float* pb  = (const float*)d_in[10];
    const int*   eidx = (const int*)d_in[11];

    const int N = in_sizes[0] / 128;
    const int E = in_sizes[11] / 2;
    const int B = (N + BNODES - 1) >> SHIFT;

    // workspace carve-out (~61 MB); X region serves pairs -> h -> rows2
    char* w = (char*)d_ws;
    unsigned short* hws = (unsigned short*)w; w += (size_t)N * 16 * 2;  // bf16 rows (32B)
    float* dinv    = (float*)w; w += (size_t)N * 4;
    int*   cnt     = (int*)w;   w += (size_t)N * 4;
    int*   row_st  = (int*)w;   w += (size_t)N * 4;
    int*   csr     = (int*)w;   w += (size_t)E * 4;
    char*  X       = w;         w += (size_t)E * 4;
    int*   bcnt    = (int*)w;   w += BMAX * 4;
    int*   bbase   = (int*)w;   w += (BMAX + 4) * 4;   // +4 keeps 16B alignment below
    int*   gcur    = (int*)w;   w += BMAX * 4;
    unsigned short* W1T = (unsigned short*)w; w += 256 * 128 * 2;  // 16B-aligned
    unsigned short* W2T = (unsigned short*)w; w += 16 * 256 * 2;

    int*          pairs = (int*)X;           // live: partition -> build_csr
    float*        h     = (float*)X;         // live: mlp -> hw1 (pairs dead)
    unsigned int* rows2 = (unsigned int*)X;  // live: gather_hw -> gather_final (h dead)

    float* out  = (float*)d_out;
    float* hout = out + N;

    const int nb_n = (N + 255) / 256;
    const int nb_g = (N * 8 + 255) / 256;
    const int nb_p = (E + PCHUNK - 1) / PCHUNK;

    // CSR chain first so dinv exists before hw folds it into the rows.
    zero_kernel<<<1, BMAX, 0, stream>>>(bcnt);
    bucket_count<<<1024, 256, 0, stream>>>(eidx, bcnt, E, N, B);
    scan_kernel<<<1, BMAX, 0, stream>>>(bcnt, bbase, gcur, B);
    partition_kernel<<<nb_p, 512, 0, stream>>>(eidx, gcur, pairs, E, N, B);
    build_csr<<<B, 512, 0, stream>>>(pairs, bbase, row_st, cnt, dinv, csr, N);

    prep_kernel<<<32, 256, 0, stream>>>(W1, W2, W1T, W2T);
    mlp_mfma<<<N / 64, 256, 0, stream>>>(x, W1T, b1, W2T, b2, h, N);   // pairs dead

    hw_kernel<<<nb_n, 256, 0, stream>>>(h, cw0, dinv, hws, N);
    gather_hw<<<nb_g, 256, 0, stream>>>(hws, dinv, csr, row_st, cnt, cb0, cw1, rows2, N); // h dead
    gather_final<<<nb_g, 256, 0, stream>>>((const unsigned short*)rows2, dinv, csr, row_st, cnt,
                                           cb1, pw, pb, out, hout, N);
}